// Round 16
// baseline (153.373 us; speedup 1.0000x reference)
//
#include <hip/hip_runtime.h>

// ---------------------------------------------------------------------------
// STRODE fused kernel for MI355X (gfx950) — round 16
// r15 base (81.3 us) + S1 on 32x32x16 MFMA with K-split wave pairs:
//   wave w: u-tile32 p=w&3 (32 u-rows), K-half h=w>>2 (256 k).
//   Each Yb read now feeds 32 u-rows (was 16) -> S1 LDS reads halve
//   (256KB -> 128KB +18KB exchange); S1 MFMA count halves (32->16/wave).
//   Partner waves (p, 0/1) exchange fp32 partials via S1x LDS (stride 72B,
//   2-way-free banks), each finishes the r-half it owns (8 tanh, 2 uint2).
//   +1 barrier/step (4 total). S2/S3/folds/padding/mfma_a: unchanged (r15).
// This round is ALSO the clean test of the 32x32 fragment layout (r10's
// only unexonerated element): A row=lane&31, k=(lane>>5)*8+e;
// D row=(r&3)+8*(r>>2)+4*(lane>>5), col=lane&31.
// ---------------------------------------------------------------------------

typedef __attribute__((ext_vector_type(8))) short s16x8;    // 8 x bf16 frag
typedef __attribute__((ext_vector_type(4))) float fx4;      // 16x16 acc
typedef __attribute__((ext_vector_type(16))) float f32x16;  // 32x32 acc

#define NB 8192
#define DD 512
#define UU 100
#define UP 128
#define BM 32
#define YSTR 1040                    // 512*2 + 16 pad
#define HSTR 272                     // 128*2 + 16 pad
#define XSTR 72                      // exchange lane stride (18 dw, 2-way free)

__device__ __forceinline__ unsigned int f2bf(float x) {
  unsigned int u = __float_as_uint(x);
  return (u + 0x7FFFu + ((u >> 16) & 1u)) >> 16;   // RNE (prep only)
}
__device__ __forceinline__ float bf2f(unsigned int h) {
  return __uint_as_float(h << 16);
}
__device__ __forceinline__ unsigned int cvt_pk_bf16(float lo, float hi) {
  unsigned int r;
  asm("v_cvt_pk_bf16_f32 %0, %1, %2" : "=v"(r) : "v"(lo), "v"(hi));
  return r;
}
__device__ __forceinline__ float tanh5(float x) {
  float e = __builtin_amdgcn_exp2f(x * 2.885390081777927f);
  return 1.0f - 2.0f / (e + 1.0f);
}
__device__ __forceinline__ fx4 mfma_a(s16x8 a, s16x8 b, fx4 c) {
  asm("v_mfma_f32_16x16x32_bf16 %0, %1, %2, %0" : "+v"(c) : "a"(a), "v"(b));
  return c;
}

// ---------------------------------------------------------------------------
// Weight prep: fp32 -> bf16, pad U=100 -> 128 with zeros.
//   W2b col 127 = b2 (pairs with H1[*][127]=1.0)
//   W3b col 127 = b3 (pairs with H2[b][127]=dt[b])
// ---------------------------------------------------------------------------
__global__ void prep_weights(const float* __restrict__ W1,
                             const float* __restrict__ W2,
                             const float* __restrict__ W3,
                             const float* __restrict__ b2,
                             const float* __restrict__ b3,
                             unsigned short* __restrict__ ws) {
  int e = blockIdx.x * 256 + threadIdx.x;
  if (e < 65536) {                        // W1b[128][512]
    int u = e >> 9, kc = e & 511;
    ws[e] = (u < UU) ? (unsigned short)f2bf(W1[u * DD + kc]) : (unsigned short)0;
  } else if (e < 81920) {                 // W2b[128][128]
    int e2 = e - 65536;
    int n = e2 >> 7, kc = e2 & 127;
    unsigned short v = 0;
    if (kc == 127)      v = (n < UU) ? (unsigned short)f2bf(b2[n]) : (unsigned short)0;
    else if (n < UU && kc < UU) v = (unsigned short)f2bf(W2[n * UU + kc]);
    ws[e] = v;
  } else if (e < 147456) {                // W3b[512][128]
    int e3 = e - 81920;
    int d = e3 >> 7, kc = e3 & 127;
    unsigned short v = 0;
    if (kc == 127)      v = (unsigned short)f2bf(b3[d]);
    else if (kc < UU)   v = (unsigned short)f2bf(W3[d * UU + kc]);
    ws[e] = v;
  }
}

// ---------------------------------------------------------------------------
// Main fused ODE kernel. grid = 256 WGs x 512 thr (8 waves), 32 rows/WG.
// ---------------------------------------------------------------------------
__global__ __launch_bounds__(512) __attribute__((amdgpu_waves_per_eu(2, 2)))
void ode_main(
    const float* __restrict__ y0, const float* __restrict__ t_seq,
    const float* __restrict__ b1,
    const unsigned short* __restrict__ W1b,
    const unsigned short* __restrict__ W2b,
    const unsigned short* __restrict__ W3b,
    const int* __restrict__ kptr, float* __restrict__ out) {
  __shared__ char Yb[BM * YSTR];       // 33.3 KB bf16 Y [32][512+pad]
  __shared__ char H1[BM * HSTR];       //  8.7 KB bf16 H1 [32][128+pad]; c127=1
  __shared__ char H2[BM * HSTR];       //  8.7 KB bf16 H2 [32][128+pad]; c127=dt
  __shared__ char S1x[4 * 64 * XSTR];  // 18.4 KB fp32 S1 partials [p][lane][f]

  const int tid  = threadIdx.x;
  const int w    = tid >> 6;           // wave 0..7
  const int lane = tid & 63;
  const int lo   = lane & 15;
  const int hi   = lane >> 4;
  const int c31  = lane & 31;
  const int h5   = lane >> 5;
  const int p    = w & 3;              // S1 u-tile32
  const int h    = w >> 2;             // S1 K-half == finish-half
  const int b0   = blockIdx.x * BM;
  const int k    = *kptr;
  const float kinv = 1.0f / (float)k;

  // lane-constant LDS bases
  const int yrb1 = c31 * YSTR + h * 512 + h5 * 16;   // S1 Yb reads
  const int ywb  = lo * YSTR + w * 128 + hi * 8;     // Yb writes
  const int hrb  = lo * HSTR + hi * 16;              // H1/H2 reads (S2/S3)
  const int hwb2 = lo * HSTR + w * 32 + hi * 8;      // H2 writes
  const int h1wb = c31 * HSTR + p * 64 + h * 32 + h5 * 8;  // H1 finisher writes
  const int xb   = p * (64 * XSTR) + lane * XSTR;    // exchange base

  // ---- register-resident weights ----------------------------------------
  s16x8 w1r[16];                     // W1 32x32 A-frags: u=p*32+c31, K-half h
#pragma unroll
  for (int kk = 0; kk < 16; ++kk)
    w1r[kk] = *(const s16x8*)(W1b + (p * 32 + c31) * DD + h * 256 + kk * 16 + h5 * 8);
  s16x8 w2r[4];                      // W2[u'=16w+lo][K=128] 16 regs
#pragma unroll
  for (int kk = 0; kk < 4; ++kk)
    w2r[kk] = *(const s16x8*)(W2b + (16 * w + lo) * UP + kk * 32 + hi * 8);
  s16x8 w3r[4][4];                   // W3[d=(4w+i)*16+lo][K=128] 64 regs
#pragma unroll
  for (int i = 0; i < 4; ++i)
#pragma unroll
    for (int kk = 0; kk < 4; ++kk)
      w3r[i][kk] = *(const s16x8*)(W3b + ((4 * w + i) * 16 + lo) * UP + kk * 32 + hi * 8);

  // ---- hoisted per-thread constants -------------------------------------
  float b1v[2][4];                   // finish-half bias: u = p*32+16h+8gg+4h5+m
#pragma unroll
  for (int gg = 0; gg < 2; ++gg)
#pragma unroll
    for (int m = 0; m < 4; ++m) {
      int u = p * 32 + 16 * h + 8 * gg + 4 * h5 + m;
      b1v[gg][m] = (u < UU) ? b1[u] : 0.0f;
    }
  float dt2[2];                      // dt for b = j*16+lo
#pragma unroll
  for (int j = 0; j < 2; ++j) {
    int b = b0 + j * 16 + lo;
    dt2[j] = (t_seq[2 * b + 1] - t_seq[2 * b]) * kinv;
  }

  // ---- persistent Y: Yr[i][j][r] = Y[b=j*16+lo][d=(4w+i)*16+hi*4+r] ------
  fx4 Yr[4][2];
#pragma unroll
  for (int i = 0; i < 4; ++i)
#pragma unroll
    for (int j = 0; j < 2; ++j) {
      const float* pp = y0 + (size_t)(b0 + j * 16 + lo) * DD + (4 * w + i) * 16 + hi * 4;
      Yr[i][j] = *(const fx4*)pp;
    }

  auto write_yb = [&]() {
#pragma unroll
    for (int i = 0; i < 4; ++i)
#pragma unroll
      for (int j = 0; j < 2; ++j) {
        uint2 q;
        q.x = cvt_pk_bf16(Yr[i][j][0], Yr[i][j][1]);
        q.y = cvt_pk_bf16(Yr[i][j][2], Yr[i][j][3]);
        *(uint2*)(Yb + ywb + i * 32 + j * 16 * YSTR) = q;
      }
  };
  write_yb();
  __syncthreads();

  const fx4 zf = {0.f, 0.f, 0.f, 0.f};

#pragma unroll 1
  for (int s = 0; s < k; ++s) {
    // ===== S1a: partial = W1[p-tile32, K-half h] * Y^T  (32x32x16) ========
    {
      f32x16 a0, a1;
#pragma unroll
      for (int r = 0; r < 16; ++r) { a0[r] = 0.0f; a1[r] = 0.0f; }
      __builtin_amdgcn_s_setprio(1);
#pragma unroll
      for (int kk = 0; kk < 16; kk += 2) {
        s16x8 f0 = *(const s16x8*)(Yb + yrb1 + kk * 32);
        s16x8 f1 = *(const s16x8*)(Yb + yrb1 + (kk + 1) * 32);
        a0 = __builtin_amdgcn_mfma_f32_32x32x16_bf16(w1r[kk], f0, a0, 0, 0, 0);
        a1 = __builtin_amdgcn_mfma_f32_32x32x16_bf16(w1r[kk + 1], f1, a1, 0, 0, 0);
      }
      __builtin_amdgcn_s_setprio(0);
      // write NON-finish half (f = 1-h) for partner; keep finish half in s[]
      float sv[8];
#pragma unroll
      for (int r = 0; r < 8; ++r) sv[r] = a0[h * 8 + r] + a1[h * 8 + r];
      fx4 o0, o1;
#pragma unroll
      for (int m = 0; m < 4; ++m) {
        o0[m] = a0[(1 - h) * 8 + m] + a1[(1 - h) * 8 + m];
        o1[m] = a0[(1 - h) * 8 + 4 + m] + a1[(1 - h) * 8 + 4 + m];
      }
      *(fx4*)(S1x + xb + (1 - h) * 32)      = o0;
      *(fx4*)(S1x + xb + (1 - h) * 32 + 16) = o1;
      __syncthreads();
      // ===== S1b: finish half h: combine partner + bias + tanh -> H1 ======
      fx4 p0 = *(const fx4*)(S1x + xb + h * 32);
      fx4 p1 = *(const fx4*)(S1x + xb + h * 32 + 16);
#pragma unroll
      for (int gg = 0; gg < 2; ++gg) {
        const fx4& pr = gg ? p1 : p0;
        float v0 = tanh5(sv[4 * gg + 0] + pr[0] + b1v[gg][0]);
        float v1 = tanh5(sv[4 * gg + 1] + pr[1] + b1v[gg][1]);
        float v2 = tanh5(sv[4 * gg + 2] + pr[2] + b1v[gg][2]);
        float v3 = tanh5(sv[4 * gg + 3] + pr[3] + b1v[gg][3]);
        if (w == 7 && h5 == 1 && gg == 1) v3 = 1.0f;   // u = 127 slot
        uint2 q;
        q.x = cvt_pk_bf16(v0, v1);
        q.y = cvt_pk_bf16(v2, v3);
        *(uint2*)(H1 + h1wb + gg * 16) = q;
      }
    }
    __syncthreads();

    // ===== S2 swapped: H2[b][u'-tile w] = tanh(W2 H1^T)*dt; H2[b][127]=dt =
    {
      fx4 c2[2];
      c2[0] = zf; c2[1] = zf;
      __builtin_amdgcn_s_setprio(1);
#pragma unroll
      for (int kk = 0; kk < 4; ++kk) {
        s16x8 hb0 = *(const s16x8*)(H1 + hrb + kk * 64);
        s16x8 hb1 = *(const s16x8*)(H1 + hrb + kk * 64 + 16 * HSTR);
        c2[0] = mfma_a(w2r[kk], hb0, c2[0]);
        c2[1] = mfma_a(w2r[kk], hb1, c2[1]);
      }
      __builtin_amdgcn_s_setprio(0);
#pragma unroll
      for (int j = 0; j < 2; ++j) {
        float h0 = tanh5(c2[j][0]) * dt2[j];
        float h1x = tanh5(c2[j][1]) * dt2[j];
        float h2x = tanh5(c2[j][2]) * dt2[j];
        float h3 = tanh5(c2[j][3]) * dt2[j];
        if (w == 7 && hi == 3) h3 = dt2[j];        // u' = 127 slot
        uint2 q;
        q.x = cvt_pk_bf16(h0, h1x);
        q.y = cvt_pk_bf16(h2x, h3);
        *(uint2*)(H2 + hwb2 + j * 16 * HSTR) = q;
      }
    }
    __syncthreads();

    // ===== S3: Yr += W3 H2^T  (b3*dt via col 127) =========================
    __builtin_amdgcn_s_setprio(1);
#pragma unroll
    for (int kk = 0; kk < 4; ++kk) {
      s16x8 bb0 = *(const s16x8*)(H2 + hrb + kk * 64);
      s16x8 bb1 = *(const s16x8*)(H2 + hrb + kk * 64 + 16 * HSTR);
#pragma unroll
      for (int i = 0; i < 4; ++i) {
        Yr[i][0] = mfma_a(w3r[i][kk], bb0, Yr[i][0]);
        Yr[i][1] = mfma_a(w3r[i][kk], bb1, Yr[i][1]);
      }
    }
    __builtin_amdgcn_s_setprio(0);
    write_yb();
    __syncthreads();
  }

  // ---- final store: coalesced fp32 from bf16 Yb -------------------------
  for (int idx = tid; idx < BM * DD; idx += 512) {
    int b = idx >> 9, d = idx & 511;
    unsigned short hx = *(const unsigned short*)(Yb + b * YSTR + 2 * d);
    out[(size_t)(b0 + b) * 513 + d] = bf2f((unsigned int)hx);
  }
}

// ---------------------------------------------------------------------------
// Loss column:  loss = ycum[-2] = 0.01 * sum_{t=1..98} gm_t   (exact algebra)
// ---------------------------------------------------------------------------
__global__ void loss_kernel(const float* __restrict__ bdp,
                            const float* __restrict__ sp,
                            const float* __restrict__ sdp,
                            float* __restrict__ out) {
  int b = blockIdx.x * 256 + threadIdx.x;
  if (b >= NB) return;
  float bd = bdp[b];
  float Kv = sp[b] + __logf(-bd + 0.01f) - __logf(sdp[b] + 0.01f);
  float acc = 0.0f;
  for (int t = 1; t <= 98; ++t) {
    float m = 0.01f * (float)t - 1.0f;     // in (-1, 0)
    float L = __logf(-m);                  // negative
    acc += (-bd) / (m * L) * (Kv - __logf(-L));
  }
  out[(size_t)b * 513 + 512] = 0.01f * acc;
}

// ---------------------------------------------------------------------------
extern "C" void kernel_launch(void* const* d_in, const int* in_sizes, int n_in,
                              void* d_out, int out_size, void* d_ws, size_t ws_size,
                              hipStream_t stream) {
  const float* y0    = (const float*)d_in[0];
  const float* t_seq = (const float*)d_in[1];
  const float* W1    = (const float*)d_in[2];
  const float* b1    = (const float*)d_in[3];
  const float* W2    = (const float*)d_in[4];
  const float* b2    = (const float*)d_in[5];
  const float* W3    = (const float*)d_in[6];
  const float* b3    = (const float*)d_in[7];
  const float* bd    = (const float*)d_in[9];
  const float* s_    = (const float*)d_in[10];
  const float* sd    = (const float*)d_in[11];
  const int*   kptr  = (const int*)d_in[12];
  float* out = (float*)d_out;
  unsigned short* ws = (unsigned short*)d_ws;

  prep_weights<<<576, 256, 0, stream>>>(W1, W2, W3, b2, b3, ws);
  ode_main<<<256, 512, 0, stream>>>(y0, t_seq, b1,
                                    ws, ws + 65536, ws + 81920, kptr, out);
  loss_kernel<<<32, 256, 0, stream>>>(bd, s_, sd, out);
}

// Round 17
// 89.936 us; speedup vs baseline: 1.7054x; 1.7054x over previous
//
#include <hip/hip_runtime.h>

// ---------------------------------------------------------------------------
// STRODE fused kernel for MI355X (gfx950) — round 17
// r16 (correct but spilled: WRITE 27.7MB, VALUBusy 57%) minus 24 regs:
//   * S1 single chained f32x16 acc (was 2) via inline-asm "+v" (VGPR-pinned,
//     no builtin AGPR shuffling), A still "a"-pinned.
//   * finish/write halves read DIRECTLY from acc under wave-uniform if(h)
//     with compile-time indices (no sv[] copy; no dynamic vector indexing).
// Everything else identical to r16 (32x32 S1 K-split pairs + exchange,
// S2-swap, col-127 folds, padding, mfma_a, 4 barriers/step).
// ---------------------------------------------------------------------------

typedef __attribute__((ext_vector_type(8))) short s16x8;    // 8 x bf16 frag
typedef __attribute__((ext_vector_type(4))) float fx4;      // 16x16 acc
typedef __attribute__((ext_vector_type(16))) float f32x16;  // 32x32 acc

#define NB 8192
#define DD 512
#define UU 100
#define UP 128
#define BM 32
#define YSTR 1040                    // 512*2 + 16 pad
#define HSTR 272                     // 128*2 + 16 pad
#define XSTR 72                      // exchange lane stride (18 dw, 2-way free)

__device__ __forceinline__ unsigned int f2bf(float x) {
  unsigned int u = __float_as_uint(x);
  return (u + 0x7FFFu + ((u >> 16) & 1u)) >> 16;   // RNE (prep only)
}
__device__ __forceinline__ float bf2f(unsigned int h) {
  return __uint_as_float(h << 16);
}
__device__ __forceinline__ unsigned int cvt_pk_bf16(float lo, float hi) {
  unsigned int r;
  asm("v_cvt_pk_bf16_f32 %0, %1, %2" : "=v"(r) : "v"(lo), "v"(hi));
  return r;
}
__device__ __forceinline__ float tanh5(float x) {
  float e = __builtin_amdgcn_exp2f(x * 2.885390081777927f);
  return 1.0f - 2.0f / (e + 1.0f);
}
__device__ __forceinline__ fx4 mfma_a(s16x8 a, s16x8 b, fx4 c) {
  asm("v_mfma_f32_16x16x32_bf16 %0, %1, %2, %0" : "+v"(c) : "a"(a), "v"(b));
  return c;
}
__device__ __forceinline__ f32x16 mfma32_a(s16x8 a, s16x8 b, f32x16 c) {
  asm("v_mfma_f32_32x32x16_bf16 %0, %1, %2, %0" : "+v"(c) : "a"(a), "v"(b));
  return c;
}

// ---------------------------------------------------------------------------
// Weight prep: fp32 -> bf16, pad U=100 -> 128 with zeros.
//   W2b col 127 = b2 (pairs with H1[*][127]=1.0)
//   W3b col 127 = b3 (pairs with H2[b][127]=dt[b])
// ---------------------------------------------------------------------------
__global__ void prep_weights(const float* __restrict__ W1,
                             const float* __restrict__ W2,
                             const float* __restrict__ W3,
                             const float* __restrict__ b2,
                             const float* __restrict__ b3,
                             unsigned short* __restrict__ ws) {
  int e = blockIdx.x * 256 + threadIdx.x;
  if (e < 65536) {                        // W1b[128][512]
    int u = e >> 9, kc = e & 511;
    ws[e] = (u < UU) ? (unsigned short)f2bf(W1[u * DD + kc]) : (unsigned short)0;
  } else if (e < 81920) {                 // W2b[128][128]
    int e2 = e - 65536;
    int n = e2 >> 7, kc = e2 & 127;
    unsigned short v = 0;
    if (kc == 127)      v = (n < UU) ? (unsigned short)f2bf(b2[n]) : (unsigned short)0;
    else if (n < UU && kc < UU) v = (unsigned short)f2bf(W2[n * UU + kc]);
    ws[e] = v;
  } else if (e < 147456) {                // W3b[512][128]
    int e3 = e - 81920;
    int d = e3 >> 7, kc = e3 & 127;
    unsigned short v = 0;
    if (kc == 127)      v = (unsigned short)f2bf(b3[d]);
    else if (kc < UU)   v = (unsigned short)f2bf(W3[d * UU + kc]);
    ws[e] = v;
  }
}

// ---------------------------------------------------------------------------
// Main fused ODE kernel. grid = 256 WGs x 512 thr (8 waves), 32 rows/WG.
// ---------------------------------------------------------------------------
__global__ __launch_bounds__(512) __attribute__((amdgpu_waves_per_eu(2, 2)))
void ode_main(
    const float* __restrict__ y0, const float* __restrict__ t_seq,
    const float* __restrict__ b1,
    const unsigned short* __restrict__ W1b,
    const unsigned short* __restrict__ W2b,
    const unsigned short* __restrict__ W3b,
    const int* __restrict__ kptr, float* __restrict__ out) {
  __shared__ char Yb[BM * YSTR];       // 33.3 KB bf16 Y [32][512+pad]
  __shared__ char H1[BM * HSTR];       //  8.7 KB bf16 H1 [32][128+pad]; c127=1
  __shared__ char H2[BM * HSTR];       //  8.7 KB bf16 H2 [32][128+pad]; c127=dt
  __shared__ char S1x[4 * 64 * XSTR];  // 18.4 KB fp32 S1 partials [p][lane][f]

  const int tid  = threadIdx.x;
  const int w    = tid >> 6;           // wave 0..7
  const int lane = tid & 63;
  const int lo   = lane & 15;
  const int hi   = lane >> 4;
  const int c31  = lane & 31;
  const int h5   = lane >> 5;
  const int p    = w & 3;              // S1 u-tile32
  const int h    = w >> 2;             // S1 K-half == finish-half
  const int b0   = blockIdx.x * BM;
  const int k    = *kptr;
  const float kinv = 1.0f / (float)k;

  // lane-constant LDS bases
  const int yrb1 = c31 * YSTR + h * 512 + h5 * 16;   // S1 Yb reads
  const int ywb  = lo * YSTR + w * 128 + hi * 8;     // Yb writes
  const int hrb  = lo * HSTR + hi * 16;              // H1/H2 reads (S2/S3)
  const int hwb2 = lo * HSTR + w * 32 + hi * 8;      // H2 writes
  const int h1wb = c31 * HSTR + p * 64 + h * 32 + h5 * 8;  // H1 finisher writes
  const int xb   = p * (64 * XSTR) + lane * XSTR;    // exchange base

  // ---- register-resident weights ----------------------------------------
  s16x8 w1r[16];                     // W1 32x32 A-frags: u=p*32+c31, K-half h
#pragma unroll
  for (int kk = 0; kk < 16; ++kk)
    w1r[kk] = *(const s16x8*)(W1b + (p * 32 + c31) * DD + h * 256 + kk * 16 + h5 * 8);
  s16x8 w2r[4];                      // W2[u'=16w+lo][K=128] 16 regs
#pragma unroll
  for (int kk = 0; kk < 4; ++kk)
    w2r[kk] = *(const s16x8*)(W2b + (16 * w + lo) * UP + kk * 32 + hi * 8);
  s16x8 w3r[4][4];                   // W3[d=(4w+i)*16+lo][K=128] 64 regs
#pragma unroll
  for (int i = 0; i < 4; ++i)
#pragma unroll
    for (int kk = 0; kk < 4; ++kk)
      w3r[i][kk] = *(const s16x8*)(W3b + ((4 * w + i) * 16 + lo) * UP + kk * 32 + hi * 8);

  // ---- hoisted per-thread constants -------------------------------------
  float b1v[2][4];                   // finish-half bias: u = p*32+16h+8gg+4h5+m
#pragma unroll
  for (int gg = 0; gg < 2; ++gg)
#pragma unroll
    for (int m = 0; m < 4; ++m) {
      int u = p * 32 + 16 * h + 8 * gg + 4 * h5 + m;
      b1v[gg][m] = (u < UU) ? b1[u] : 0.0f;
    }
  float dt2[2];                      // dt for b = j*16+lo
#pragma unroll
  for (int j = 0; j < 2; ++j) {
    int b = b0 + j * 16 + lo;
    dt2[j] = (t_seq[2 * b + 1] - t_seq[2 * b]) * kinv;
  }

  // ---- persistent Y: Yr[i][j][r] = Y[b=j*16+lo][d=(4w+i)*16+hi*4+r] ------
  fx4 Yr[4][2];
#pragma unroll
  for (int i = 0; i < 4; ++i)
#pragma unroll
    for (int j = 0; j < 2; ++j) {
      const float* pp = y0 + (size_t)(b0 + j * 16 + lo) * DD + (4 * w + i) * 16 + hi * 4;
      Yr[i][j] = *(const fx4*)pp;
    }

  auto write_yb = [&]() {
#pragma unroll
    for (int i = 0; i < 4; ++i)
#pragma unroll
      for (int j = 0; j < 2; ++j) {
        uint2 q;
        q.x = cvt_pk_bf16(Yr[i][j][0], Yr[i][j][1]);
        q.y = cvt_pk_bf16(Yr[i][j][2], Yr[i][j][3]);
        *(uint2*)(Yb + ywb + i * 32 + j * 16 * YSTR) = q;
      }
  };
  write_yb();
  __syncthreads();

  const fx4 zf = {0.f, 0.f, 0.f, 0.f};

#pragma unroll 1
  for (int s = 0; s < k; ++s) {
    // ===== S1a: partial = W1[p-tile32, K-half h] * Y^T  (32x32x16) ========
    {
      f32x16 a0;
#pragma unroll
      for (int r = 0; r < 16; ++r) a0[r] = 0.0f;
      __builtin_amdgcn_s_setprio(1);
#pragma unroll
      for (int kk = 0; kk < 16; ++kk) {
        s16x8 f0 = *(const s16x8*)(Yb + yrb1 + kk * 32);
        a0 = mfma32_a(w1r[kk], f0, a0);
      }
      __builtin_amdgcn_s_setprio(0);
      // write NON-finish half (1-h) for partner (compile-time indices)
      {
        fx4 o0, o1;
        if (h == 0) {
          o0[0] = a0[8];  o0[1] = a0[9];  o0[2] = a0[10]; o0[3] = a0[11];
          o1[0] = a0[12]; o1[1] = a0[13]; o1[2] = a0[14]; o1[3] = a0[15];
        } else {
          o0[0] = a0[0];  o0[1] = a0[1];  o0[2] = a0[2];  o0[3] = a0[3];
          o1[0] = a0[4];  o1[1] = a0[5];  o1[2] = a0[6];  o1[3] = a0[7];
        }
        *(fx4*)(S1x + xb + (1 - h) * 32)      = o0;
        *(fx4*)(S1x + xb + (1 - h) * 32 + 16) = o1;
      }
      __syncthreads();
      // ===== S1b: finish half h: combine partner + bias + tanh -> H1 ======
      fx4 p0 = *(const fx4*)(S1x + xb + h * 32);
      fx4 p1 = *(const fx4*)(S1x + xb + h * 32 + 16);
      float fv[8];
      if (h == 0) {
        fv[0] = a0[0]; fv[1] = a0[1]; fv[2] = a0[2]; fv[3] = a0[3];
        fv[4] = a0[4]; fv[5] = a0[5]; fv[6] = a0[6]; fv[7] = a0[7];
      } else {
        fv[0] = a0[8];  fv[1] = a0[9];  fv[2] = a0[10]; fv[3] = a0[11];
        fv[4] = a0[12]; fv[5] = a0[13]; fv[6] = a0[14]; fv[7] = a0[15];
      }
#pragma unroll
      for (int gg = 0; gg < 2; ++gg) {
        const fx4& pr = gg ? p1 : p0;
        float v0 = tanh5(fv[4 * gg + 0] + pr[0] + b1v[gg][0]);
        float v1 = tanh5(fv[4 * gg + 1] + pr[1] + b1v[gg][1]);
        float v2 = tanh5(fv[4 * gg + 2] + pr[2] + b1v[gg][2]);
        float v3 = tanh5(fv[4 * gg + 3] + pr[3] + b1v[gg][3]);
        if (w == 7 && h5 == 1 && gg == 1) v3 = 1.0f;   // u = 127 slot
        uint2 q;
        q.x = cvt_pk_bf16(v0, v1);
        q.y = cvt_pk_bf16(v2, v3);
        *(uint2*)(H1 + h1wb + gg * 16) = q;
      }
    }
    __syncthreads();

    // ===== S2 swapped: H2[b][u'-tile w] = tanh(W2 H1^T)*dt; H2[b][127]=dt =
    {
      fx4 c2[2];
      c2[0] = zf; c2[1] = zf;
      __builtin_amdgcn_s_setprio(1);
#pragma unroll
      for (int kk = 0; kk < 4; ++kk) {
        s16x8 hb0 = *(const s16x8*)(H1 + hrb + kk * 64);
        s16x8 hb1 = *(const s16x8*)(H1 + hrb + kk * 64 + 16 * HSTR);
        c2[0] = mfma_a(w2r[kk], hb0, c2[0]);
        c2[1] = mfma_a(w2r[kk], hb1, c2[1]);
      }
      __builtin_amdgcn_s_setprio(0);
#pragma unroll
      for (int j = 0; j < 2; ++j) {
        float h0 = tanh5(c2[j][0]) * dt2[j];
        float h1x = tanh5(c2[j][1]) * dt2[j];
        float h2x = tanh5(c2[j][2]) * dt2[j];
        float h3 = tanh5(c2[j][3]) * dt2[j];
        if (w == 7 && hi == 3) h3 = dt2[j];        // u' = 127 slot
        uint2 q;
        q.x = cvt_pk_bf16(h0, h1x);
        q.y = cvt_pk_bf16(h2x, h3);
        *(uint2*)(H2 + hwb2 + j * 16 * HSTR) = q;
      }
    }
    __syncthreads();

    // ===== S3: Yr += W3 H2^T  (b3*dt via col 127) =========================
    __builtin_amdgcn_s_setprio(1);
#pragma unroll
    for (int kk = 0; kk < 4; ++kk) {
      s16x8 bb0 = *(const s16x8*)(H2 + hrb + kk * 64);
      s16x8 bb1 = *(const s16x8*)(H2 + hrb + kk * 64 + 16 * HSTR);
#pragma unroll
      for (int i = 0; i < 4; ++i) {
        Yr[i][0] = mfma_a(w3r[i][kk], bb0, Yr[i][0]);
        Yr[i][1] = mfma_a(w3r[i][kk], bb1, Yr[i][1]);
      }
    }
    __builtin_amdgcn_s_setprio(0);
    write_yb();
    __syncthreads();
  }

  // ---- final store: coalesced fp32 from bf16 Yb -------------------------
  for (int idx = tid; idx < BM * DD; idx += 512) {
    int b = idx >> 9, d = idx & 511;
    unsigned short hx = *(const unsigned short*)(Yb + b * YSTR + 2 * d);
    out[(size_t)(b0 + b) * 513 + d] = bf2f((unsigned int)hx);
  }
}

// ---------------------------------------------------------------------------
// Loss column:  loss = ycum[-2] = 0.01 * sum_{t=1..98} gm_t   (exact algebra)
// ---------------------------------------------------------------------------
__global__ void loss_kernel(const float* __restrict__ bdp,
                            const float* __restrict__ sp,
                            const float* __restrict__ sdp,
                            float* __restrict__ out) {
  int b = blockIdx.x * 256 + threadIdx.x;
  if (b >= NB) return;
  float bd = bdp[b];
  float Kv = sp[b] + __logf(-bd + 0.01f) - __logf(sdp[b] + 0.01f);
  float acc = 0.0f;
  for (int t = 1; t <= 98; ++t) {
    float m = 0.01f * (float)t - 1.0f;     // in (-1, 0)
    float L = __logf(-m);                  // negative
    acc += (-bd) / (m * L) * (Kv - __logf(-L));
  }
  out[(size_t)b * 513 + 512] = 0.01f * acc;
}

// ---------------------------------------------------------------------------
extern "C" void kernel_launch(void* const* d_in, const int* in_sizes, int n_in,
                              void* d_out, int out_size, void* d_ws, size_t ws_size,
                              hipStream_t stream) {
  const float* y0    = (const float*)d_in[0];
  const float* t_seq = (const float*)d_in[1];
  const float* W1    = (const float*)d_in[2];
  const float* b1    = (const float*)d_in[3];
  const float* W2    = (const float*)d_in[4];
  const float* b2    = (const float*)d_in[5];
  const float* W3    = (const float*)d_in[6];
  const float* b3    = (const float*)d_in[7];
  const float* bd    = (const float*)d_in[9];
  const float* s_    = (const float*)d_in[10];
  const float* sd    = (const float*)d_in[11];
  const int*   kptr  = (const int*)d_in[12];
  float* out = (float*)d_out;
  unsigned short* ws = (unsigned short*)d_ws;

  prep_weights<<<576, 256, 0, stream>>>(W1, W2, W3, b2, b3, ws);
  ode_main<<<256, 512, 0, stream>>>(y0, t_seq, b1,
                                    ws, ws + 65536, ws + 81920, kptr, out);
  loss_kernel<<<32, 256, 0, stream>>>(bd, s_, sd, out);
}